// Round 9
// baseline (1519.826 us; speedup 1.0000x reference)
//
#include <hip/hip_runtime.h>
#include <float.h>

#define B8 8
#define NPTS 4096

// ---------------- split x[B,6,N] -> xyz[B,N,3], nrm[B,N,3] ----------------
__global__ void split_xyz_kernel(const float* __restrict__ x,
                                 float* __restrict__ xyz, float* __restrict__ nrm) {
  int g = blockIdx.x * 256 + threadIdx.x;
  if (g >= B8 * NPTS) return;
  int b = g / NPTS, n = g % NPTS;
  const float* xb = x + (size_t)b * 6 * NPTS;
  float* o1 = xyz + (size_t)g * 3;
  float* o2 = nrm + (size_t)g * 3;
  o1[0] = xb[0 * NPTS + n]; o1[1] = xb[1 * NPTS + n]; o1[2] = xb[2 * NPTS + n];
  o2[0] = xb[3 * NPTS + n]; o2[1] = xb[4 * NPTS + n]; o2[2] = xb[5 * NPTS + n];
}

// ---------------- DPP helpers ----------------
template <int CTRL, int RM>
__device__ __forceinline__ unsigned dppmov(unsigned v) {
  return (unsigned)__builtin_amdgcn_update_dpp((int)v, (int)v, CTRL, RM, 0xf, false);
}

template <int CTRL, int RM>
__device__ __forceinline__ void red_key_max(unsigned& kh, unsigned& kl) {
  unsigned oh = dppmov<CTRL, RM>(kh);
  unsigned ol = dppmov<CTRL, RM>(kl);
  unsigned long long ko = ((unsigned long long)oh << 32) | ol;
  unsigned long long k  = ((unsigned long long)kh << 32) | kl;
  bool c = ko > k;
  kh = c ? oh : kh;
  kl = c ? ol : kl;
}

template <int CTRL, int RM>
__device__ __forceinline__ void red_key_min(unsigned& kh, unsigned& kl) {
  unsigned oh = dppmov<CTRL, RM>(kh);
  unsigned ol = dppmov<CTRL, RM>(kl);
  unsigned long long ko = ((unsigned long long)oh << 32) | ol;
  unsigned long long k  = ((unsigned long long)kh << 32) | kl;
  bool c = ko < k;
  kh = c ? oh : kh;
  kl = c ? ol : kl;
}

#define WAVE_RED_MAX(kh, kl)            \
  red_key_max<0x111, 0xf>(kh, kl);      \
  red_key_max<0x112, 0xf>(kh, kl);      \
  red_key_max<0x114, 0xf>(kh, kl);      \
  red_key_max<0x118, 0xf>(kh, kl);      \
  red_key_max<0x142, 0xa>(kh, kl);      \
  red_key_max<0x143, 0xc>(kh, kl);

#define WAVE_RED_MIN(kh, kl)            \
  red_key_min<0x111, 0xf>(kh, kl);      \
  red_key_min<0x112, 0xf>(kh, kl);      \
  red_key_min<0x114, 0xf>(kh, kl);      \
  red_key_min<0x118, 0xf>(kh, kl);      \
  red_key_min<0x142, 0xa>(kh, kl);      \
  red_key_min<0x143, 0xc>(kh, kl);

// ---------------- FPS (SA1 only; deeper levels are prefixes of x1) ----------------
// Hybrid of the two best measured variants: float-compare j-select (per-thread
// idx strictly increasing -> strict > gives tie->lowest free) + R6-style
// cross-wave stage (ulonglong2 broadcast reads + compare chain).
template <int BLOCK, int P>
__global__ __launch_bounds__(BLOCK) void fps4_kernel(const float* __restrict__ xyz,
                                                     int N, int S,
                                                     float* __restrict__ out_xyz) {
#pragma clang fp contract(off)
  constexpr int NW = BLOCK / 64;
  __shared__ float4 pts[BLOCK * P];
  __shared__ float4 sel[512];
  __shared__ alignas(16) unsigned long long wkey[2][NW];
  int b = blockIdx.x, t = threadIdx.x;
  const float* p = xyz + (size_t)b * N * 3;
  float px[P], py[P], pz[P], dist[P];
#pragma unroll
  for (int j = 0; j < P; ++j) {
    int idx = t + j * BLOCK;
    float a = p[3 * idx], bb = p[3 * idx + 1], c = p[3 * idx + 2];
    px[j] = a; py[j] = bb; pz[j] = c;
    pts[idx] = make_float4(a, bb, c, 0.f);
    dist[j] = 1e10f;
  }
  __syncthreads();
  float fx = p[0], fy = p[1], fz = p[2];
  for (int i = 0; i < S; ++i) {
    if (t == 0) sel[i] = make_float4(fx, fy, fz, 0.f);
    float bv = -1.0f;
    int bj = 0;
#pragma unroll
    for (int j = 0; j < P; ++j) {
      float dx = px[j] - fx, dy = py[j] - fy, dz = pz[j] - fz;
      float d = dx * dx + dy * dy + dz * dz;
      float nd = fminf(dist[j], d);
      dist[j] = nd;
      bool c = nd > bv;
      bv = c ? nd : bv;
      bj = c ? j : bj;
    }
    unsigned kh = __float_as_uint(bv);
    unsigned kl = (unsigned)(~(t + bj * BLOCK));
    WAVE_RED_MAX(kh, kl);
    int buf = i & 1;
    if ((t & 63) == 63)
      wkey[buf][t >> 6] = ((unsigned long long)kh << 32) | kl;
    __syncthreads();
    unsigned long long g = 0ull;
    const ulonglong2* wk2 = (const ulonglong2*)&wkey[buf][0];
#pragma unroll
    for (int w = 0; w < NW / 2; ++w) {
      ulonglong2 e = wk2[w];
      unsigned long long m = (e.x > e.y) ? e.x : e.y;
      g = (m > g) ? m : g;
    }
    int far = (int)~(unsigned)g;
    float4 f = pts[far];
    fx = f.x; fy = f.y; fz = f.z;
  }
  __syncthreads();
  for (int i = t; i < S; i += BLOCK) {
    float4 f = sel[i];
    float* o = out_xyz + ((size_t)b * S + i) * 3;
    o[0] = f.x; o[1] = f.y; o[2] = f.z;
  }
}

// ---------------- kNN k=20: one wave/query ----------------
__global__ __launch_bounds__(64) void knn20_kernel(const float* __restrict__ q,
                                                   const float* __restrict__ ref,
                                                   int S, int M, int* __restrict__ nidx,
                                                   int LDQ, int LDR) {
#pragma clang fp contract(off)
  int bs = blockIdx.x;
  int b = bs / S, s = bs % S;
  int t = threadIdx.x;
  __shared__ float sd[4096];
  const float* qp = q + ((size_t)b * LDQ + s) * 3;
  float qx = qp[0], qy = qp[1], qz = qp[2];
  float qq = qx * qx + qy * qy + qz * qz;
  const float* rp = ref + (size_t)b * LDR * 3;
  for (int i = t; i < M; i += 64) {
    float rx = rp[3 * i], ry = rp[3 * i + 1], rz = rp[3 * i + 2];
    float rr = rx * rx + ry * ry + rz * rz;
    float dot = qx * rx + qy * ry + qz * rz;
    sd[i] = qq - 2.0f * dot + rr;
  }
  __syncthreads();
  unsigned keep = 0;
  for (int k = 0; k < 20; ++k) {
    float bv = FLT_MAX;
    int bi = 0;
    for (int i = t; i < M; i += 64) {
      float v = sd[i];
      bool c = v < bv;
      bv = c ? v : bv;
      bi = c ? i : bi;
    }
    unsigned kh = __float_as_uint(bv), kl = (unsigned)bi;
    WAVE_RED_MIN(kh, kl);
    unsigned w = (unsigned)__builtin_amdgcn_readlane((int)kl, 63);
    if (t == k) keep = w;
    if (t == 0) sd[w] = FLT_MAX;
    __syncthreads();
  }
  if (t < 20) nidx[(size_t)bs * 20 + t] = (int)keep;
}

// ---------------- templated double-buffered GEMM core ----------------
// 64x64 tile, BK k-slab, 256 threads, 4x4 microtile. Register-staged dbuf:
// stage k0+BK while computing k0 from LDS; one barrier per k-step.
template <int BK, class AFn>
__device__ __forceinline__ void gemm_core(AFn loadA, const float* __restrict__ Wm,
                                          const float* __restrict__ bias,
                                          float* __restrict__ C,
                                          int Mrows, int N, int K, int RELU) {
  constexpr int NL = BK / 4;
  __shared__ alignas(16) float As[2][BK][68];
  __shared__ alignas(16) float Bs[2][BK][64];
  int tx = threadIdx.x & 15, ty = threadIdx.x >> 4;
  int rowBase = blockIdx.y * 64;
  int colBase = blockIdx.x * 64;
  float acc[4][4] = {};
  float areg[NL], breg[NL];

  auto stage = [&](int k0) {
#pragma unroll
    for (int u = 0; u < NL; ++u) {
      int l = (int)threadIdx.x + u * 256;
      int m = l / BK, kk = l % BK;
      int rr = rowBase + m, kq = k0 + kk;
      areg[u] = (rr < Mrows && kq < K) ? loadA(rr, kq) : 0.0f;
    }
#pragma unroll
    for (int u = 0; u < NL; ++u) {
      int l = (int)threadIdx.x + u * 256;
      int kk = l >> 6, n = l & 63;
      int kq = k0 + kk, cc = colBase + n;
      breg[u] = (kq < K && cc < N) ? Wm[(size_t)kq * N + cc] : 0.0f;
    }
  };
  auto writeLds = [&](int buf) {
#pragma unroll
    for (int u = 0; u < NL; ++u) {
      int l = (int)threadIdx.x + u * 256;
      As[buf][l % BK][l / BK] = areg[u];
    }
#pragma unroll
    for (int u = 0; u < NL; ++u) {
      int l = (int)threadIdx.x + u * 256;
      Bs[buf][l >> 6][l & 63] = breg[u];
    }
  };

  stage(0);
  writeLds(0);
  __syncthreads();
  int cur = 0;
  for (int k0 = 0; k0 < K; k0 += BK) {
    bool more = (k0 + BK < K);
    if (more) stage(k0 + BK);
#pragma unroll
    for (int kk = 0; kk < BK; ++kk) {
      const float4 av = *reinterpret_cast<const float4*>(&As[cur][kk][ty * 4]);
      const float4 bv = *reinterpret_cast<const float4*>(&Bs[cur][kk][tx * 4]);
      acc[0][0] += av.x * bv.x; acc[0][1] += av.x * bv.y;
      acc[0][2] += av.x * bv.z; acc[0][3] += av.x * bv.w;
      acc[1][0] += av.y * bv.x; acc[1][1] += av.y * bv.y;
      acc[1][2] += av.y * bv.z; acc[1][3] += av.y * bv.w;
      acc[2][0] += av.z * bv.x; acc[2][1] += av.z * bv.y;
      acc[2][2] += av.z * bv.z; acc[2][3] += av.z * bv.w;
      acc[3][0] += av.w * bv.x; acc[3][1] += av.w * bv.y;
      acc[3][2] += av.w * bv.z; acc[3][3] += av.w * bv.w;
    }
    if (more) writeLds(cur ^ 1);
    __syncthreads();
    cur ^= 1;
  }
#pragma unroll
  for (int i = 0; i < 4; ++i) {
    int row = rowBase + ty * 4 + i;
    if (row >= Mrows) continue;
#pragma unroll
    for (int j = 0; j < 4; ++j) {
      int col = colBase + tx * 4 + j;
      if (col >= N) continue;
      float v = acc[i][j] + bias[col];
      if (RELU) v = fmaxf(v, 0.0f);
      C[(size_t)row * N + col] = v;
    }
  }
}

// plain GEMM (seg head)
template <int BK>
__global__ __launch_bounds__(256) void gemm_plain_kernel(
    const float* __restrict__ A, const float* __restrict__ Wm,
    const float* __restrict__ bias, float* __restrict__ C,
    int Mrows, int N, int K, int RELU) {
  auto loadA = [&](int rr, int kq) -> float { return A[(size_t)rr * K + kq]; };
  gemm_core<BK>(loadA, Wm, bias, C, Mrows, N, K, RELU);
}

// SA GEMM with fused grouping gather
template <int BK>
__global__ __launch_bounds__(256) void gemm_sa_kernel(
    const float* __restrict__ xyz, const float* __restrict__ feats,
    const float* __restrict__ new_xyz, const int* __restrict__ nidx,
    const float* __restrict__ Wm, const float* __restrict__ bias,
    float* __restrict__ C, int Mref, int LDR, int S, int LDQ, int Cf,
    int Mrows, int N, int K) {
  auto loadA = [&](int rr, int kq) -> float {
    int bs = rr / 20;
    int s_ = bs % S;
    int b = bs / S;
    int id = nidx[rr];
    if (kq < 3)
      return xyz[((size_t)b * LDR + id) * 3 + kq] - new_xyz[((size_t)b * LDQ + s_) * 3 + kq];
    return feats[((size_t)b * Mref + id) * Cf + (kq - 3)];
  };
  gemm_core<BK>(loadA, Wm, bias, C, Mrows, N, K, 1);
}

// FP GEMM with fused 3-NN interp + skip concat
template <int BK>
__global__ __launch_bounds__(256) void gemm_fp_kernel(
    const float* __restrict__ fr, const int* __restrict__ idx3,
    const float* __restrict__ w3, const float* __restrict__ skip,
    const float* __restrict__ cls, const float* __restrict__ xyzq,
    const float* __restrict__ nrmq,
    const float* __restrict__ Wm, const float* __restrict__ bias,
    float* __restrict__ C, int Sq, int Mr, int Cr, int Cs, int mode,
    int Mrows, int N, int K) {
  auto loadA = [&](int rr, int kq) -> float {
    int bs = rr;
    int b = bs / Sq;
    if (kq < Cr) {
      const int* ii = idx3 + (size_t)bs * 3;
      const float* ww = w3 + (size_t)bs * 3;
      const float* fb = fr + (size_t)b * Mr * Cr;
      float v = ww[0] * fb[(size_t)ii[0] * Cr + kq];
      v += ww[1] * fb[(size_t)ii[1] * Cr + kq];
      v += ww[2] * fb[(size_t)ii[2] * Cr + kq];
      return v;
    }
    int cc = kq - Cr;
    if (mode == 0) return skip[(size_t)bs * Cs + cc];
    if (cc < 16) return cls[(size_t)b * 16 + cc];
    if (cc < 19) return xyzq[(size_t)bs * 3 + (cc - 16)];
    return nrmq[(size_t)bs * 3 + (cc - 19)];
  };
  gemm_core<BK>(loadA, Wm, bias, C, Mrows, N, K, 1);
}

// ---------------- maxpool over K=20 neighbors ----------------
__global__ void maxpool_kernel(const float* __restrict__ H, int SB, int C,
                               float* __restrict__ f) {
  int g = blockIdx.x * 256 + threadIdx.x;
  if (g >= SB * C) return;
  int d = g % C;
  int bs = g / C;
  const float* h = H + (size_t)bs * 20 * C + d;
  float m = h[0];
#pragma unroll
  for (int k = 1; k < 20; ++k) m = fmaxf(m, h[(size_t)k * C]);
  f[g] = m;
}

// ---------------- kNN k=3, LDS-staged refs (block-uniform batch) ----------------
__global__ __launch_bounds__(256) void knn3_lds_kernel(
    const float* __restrict__ q, const float* __restrict__ ref,
    int Sq, int M, int* __restrict__ idx3, float* __restrict__ w3,
    int LDQ, int LDR) {
#pragma clang fp contract(off)
  __shared__ float4 rpts[512];
  int g = blockIdx.x * 256 + threadIdx.x;
  int b = g / Sq, s = g % Sq;
  const float* rp = ref + (size_t)b * LDR * 3;
  for (int i = threadIdx.x; i < M; i += 256) {
    float rx = rp[3 * i], ry = rp[3 * i + 1], rz = rp[3 * i + 2];
    rpts[i] = make_float4(rx, ry, rz, rx * rx + ry * ry + rz * rz);
  }
  __syncthreads();
  const float* qp = q + ((size_t)b * LDQ + s) * 3;
  float qx = qp[0], qy = qp[1], qz = qp[2];
  float qq = qx * qx + qy * qy + qz * qz;
  float v0 = FLT_MAX, v1 = FLT_MAX, v2 = FLT_MAX;
  int i0 = 0, i1 = 0, i2 = 0;
  for (int i = 0; i < M; ++i) {
    float4 r = rpts[i];
    float d = qq - 2.0f * (qx * r.x + qy * r.y + qz * r.z) + r.w;
    if (d < v2) {
      if (d < v1) {
        if (d < v0) { v2 = v1; i2 = i1; v1 = v0; i1 = i0; v0 = d; i0 = i; }
        else { v2 = v1; i2 = i1; v1 = d; i1 = i; }
      } else { v2 = d; i2 = i; }
    }
  }
  int ii[3] = {i0, i1, i2};
  float w[3];
  float wsum = 0.0f;
#pragma unroll
  for (int k = 0; k < 3; ++k) {
    float4 r = rpts[ii[k]];
    float dx = r.x - qx, dy = r.y - qy, dz = r.z - qz;
    float d = dx * dx + dy * dy + dz * dz;
    w[k] = 1.0f / (d + 1e-8f);
    wsum += w[k];
  }
#pragma unroll
  for (int k = 0; k < 3; ++k) {
    idx3[(size_t)g * 3 + k] = ii[k];
    w3[(size_t)g * 3 + k] = w[k] / wsum;
  }
}

// ---------------- kNN k=3, per-thread VMEM scan (small / non-uniform) ----------------
__global__ void knn3_kernel(const float* __restrict__ q, const float* __restrict__ ref,
                            int Sq, int M, int* __restrict__ idx3, float* __restrict__ w3,
                            int total, int LDQ, int LDR) {
#pragma clang fp contract(off)
  int g = blockIdx.x * 256 + threadIdx.x;
  if (g >= total) return;
  int b = g / Sq, s = g % Sq;
  const float* qp = q + ((size_t)b * LDQ + s) * 3;
  float qx = qp[0], qy = qp[1], qz = qp[2];
  float qq = qx * qx + qy * qy + qz * qz;
  const float* rp = ref + (size_t)b * LDR * 3;
  float v0 = FLT_MAX, v1 = FLT_MAX, v2 = FLT_MAX;
  int i0 = 0, i1 = 0, i2 = 0;
  for (int i = 0; i < M; ++i) {
    float rx = rp[3 * i], ry = rp[3 * i + 1], rz = rp[3 * i + 2];
    float d = qq - 2.0f * (qx * rx + qy * ry + qz * rz) + (rx * rx + ry * ry + rz * rz);
    if (d < v2) {
      if (d < v1) {
        if (d < v0) { v2 = v1; i2 = i1; v1 = v0; i1 = i0; v0 = d; i0 = i; }
        else { v2 = v1; i2 = i1; v1 = d; i1 = i; }
      } else { v2 = d; i2 = i; }
    }
  }
  int ii[3] = {i0, i1, i2};
  float w[3];
  float wsum = 0.0f;
#pragma unroll
  for (int k = 0; k < 3; ++k) {
    const float* r = rp + (size_t)ii[k] * 3;
    float dx = r[0] - qx, dy = r[1] - qy, dz = r[2] - qz;
    float d = dx * dx + dy * dy + dz * dz;
    w[k] = 1.0f / (d + 1e-8f);
    wsum += w[k];
  }
#pragma unroll
  for (int k = 0; k < 3; ++k) {
    idx3[(size_t)g * 3 + k] = ii[k];
    w3[(size_t)g * 3 + k] = w[k] / wsum;
  }
}

// ---------------- transpose g0 [B,N,128] -> out2 [B,128,N] ----------------
__global__ __launch_bounds__(256) void transpose_g0_kernel(const float* __restrict__ g0,
                                                           float* __restrict__ out2) {
  __shared__ float tile[32][33];
  int n0 = blockIdx.x * 32, c0 = blockIdx.y * 32, b = blockIdx.z;
  int tx = threadIdx.x & 31, ty = threadIdx.x >> 5;
#pragma unroll
  for (int j = 0; j < 32; j += 8)
    tile[ty + j][tx] = g0[((size_t)b * NPTS + n0 + ty + j) * 128 + c0 + tx];
  __syncthreads();
#pragma unroll
  for (int j = 0; j < 32; j += 8)
    out2[((size_t)b * 128 + c0 + ty + j) * NPTS + n0 + tx] = tile[tx][ty + j];
}

// ---------------- host-side orchestration ----------------
static inline int cdiv(int a, int b) { return (a + b - 1) / b; }

extern "C" void kernel_launch(void* const* d_in, const int* in_sizes, int n_in,
                              void* d_out, int out_size, void* d_ws, size_t ws_size,
                              hipStream_t stream) {
  const float* x    = (const float*)d_in[0];
  const float* cls  = (const float*)d_in[1];
  const float* W0 = (const float*)d_in[2];  const float* b0 = (const float*)d_in[3];
  const float* W1 = (const float*)d_in[4];  const float* b1 = (const float*)d_in[5];
  const float* W2 = (const float*)d_in[6];  const float* b2 = (const float*)d_in[7];
  const float* W3 = (const float*)d_in[8];  const float* b3 = (const float*)d_in[9];
  const float* F3 = (const float*)d_in[10]; const float* fb3 = (const float*)d_in[11];
  const float* F2 = (const float*)d_in[12]; const float* fb2 = (const float*)d_in[13];
  const float* F1 = (const float*)d_in[14]; const float* fb1 = (const float*)d_in[15];
  const float* F0 = (const float*)d_in[16]; const float* fb0 = (const float*)d_in[17];
  const float* Wseg = (const float*)d_in[18]; const float* bseg = (const float*)d_in[19];
  float* out = (float*)d_out;

  float* ws = (float*)d_ws;
  size_t off = 0;
  auto alloc = [&](size_t n) { float* p = ws + off; off += (n + 3) & ~(size_t)3; return p; };
  float* xyz = alloc(8 * 4096 * 3);
  float* nrm = alloc(8 * 4096 * 3);
  float* x1 = alloc(8 * 512 * 3);          // x2/x3/x4 are per-batch PREFIXES of x1
  float* f1 = alloc(8 * 512 * 64);
  float* f2 = alloc(8 * 256 * 128);
  float* f3 = alloc(8 * 128 * 256);
  float* f4 = alloc(8 * 64 * 512);
  float* g3 = alloc(8 * 128 * 512);
  float* g2 = alloc(8 * 256 * 256);
  float* g1 = alloc(8 * 512 * 128);
  float* g0 = alloc(8 * 4096 * 128);
  float* w3buf = alloc(8 * 4096 * 3);
  float* Hbuf = alloc(8 * 512 * 20 * 64);
  int* nidx = (int*)alloc(8 * 512 * 20);
  int* idx3 = (int*)alloc(8 * 4096 * 3);

  split_xyz_kernel<<<cdiv(8 * 4096, 256), 256, 0, stream>>>(x, xyz, nrm);

  // ---- SA1: 4096 -> 512, Cin 6 -> 64 ----
  fps4_kernel<256, 16><<<8, 256, 0, stream>>>(xyz, 4096, 512, x1);
  knn20_kernel<<<8 * 512, 64, 0, stream>>>(x1, xyz, 512, 4096, nidx, 512, 4096);
  {
    dim3 grid(1, cdiv(8 * 512 * 20, 64));
    gemm_sa_kernel<8><<<grid, 256, 0, stream>>>(xyz, nrm, x1, nidx, W0, b0, Hbuf,
                                                4096, 4096, 512, 512, 3,
                                                8 * 512 * 20, 64, 6);
    maxpool_kernel<<<cdiv(8 * 512 * 64, 256), 256, 0, stream>>>(Hbuf, 8 * 512, 64, f1);
  }

  // ---- SA2: Cin 67 -> 128 ----
  knn20_kernel<<<8 * 256, 64, 0, stream>>>(x1, x1, 256, 512, nidx, 512, 512);
  {
    dim3 grid(2, cdiv(8 * 256 * 20, 64));
    gemm_sa_kernel<16><<<grid, 256, 0, stream>>>(x1, f1, x1, nidx, W1, b1, Hbuf,
                                                 512, 512, 256, 512, 64,
                                                 8 * 256 * 20, 128, 67);
    maxpool_kernel<<<cdiv(8 * 256 * 128, 256), 256, 0, stream>>>(Hbuf, 8 * 256, 128, f2);
  }

  // ---- SA3: Cin 131 -> 256 ----
  knn20_kernel<<<8 * 128, 64, 0, stream>>>(x1, x1, 128, 256, nidx, 512, 512);
  {
    dim3 grid(4, cdiv(8 * 128 * 20, 64));
    gemm_sa_kernel<32><<<grid, 256, 0, stream>>>(x1, f2, x1, nidx, W2, b2, Hbuf,
                                                 256, 512, 128, 512, 128,
                                                 8 * 128 * 20, 256, 131);
    maxpool_kernel<<<cdiv(8 * 128 * 256, 256), 256, 0, stream>>>(Hbuf, 8 * 128, 256, f3);
  }

  // ---- SA4: Cin 259 -> 512 ----
  knn20_kernel<<<8 * 64, 64, 0, stream>>>(x1, x1, 64, 128, nidx, 512, 512);
  {
    dim3 grid(8, cdiv(8 * 64 * 20, 64));
    gemm_sa_kernel<32><<<grid, 256, 0, stream>>>(x1, f3, x1, nidx, W3, b3, Hbuf,
                                                 128, 512, 64, 512, 256,
                                                 8 * 64 * 20, 512, 259);
    maxpool_kernel<<<cdiv(8 * 64 * 512, 256), 256, 0, stream>>>(Hbuf, 8 * 64, 512, f4);
  }

  // ---- FP3 ----
  knn3_kernel<<<cdiv(8 * 128, 256), 256, 0, stream>>>(x1, x1, 128, 64, idx3, w3buf,
                                                      8 * 128, 512, 512);
  {
    dim3 grid(8, cdiv(8 * 128, 64));
    gemm_fp_kernel<32><<<grid, 256, 0, stream>>>(f4, idx3, w3buf, f3, nullptr, nullptr, nullptr,
                                                 F3, fb3, g3, 128, 64, 512, 256, 0,
                                                 8 * 128, 512, 768);
  }

  // ---- FP2 ----
  knn3_lds_kernel<<<8, 256, 0, stream>>>(x1, x1, 256, 128, idx3, w3buf, 512, 512);
  {
    dim3 grid(4, cdiv(8 * 256, 64));
    gemm_fp_kernel<32><<<grid, 256, 0, stream>>>(g3, idx3, w3buf, f2, nullptr, nullptr, nullptr,
                                                 F2, fb2, g2, 256, 128, 512, 128, 0,
                                                 8 * 256, 256, 640);
  }

  // ---- FP1 ----
  knn3_lds_kernel<<<16, 256, 0, stream>>>(x1, x1, 512, 256, idx3, w3buf, 512, 512);
  {
    dim3 grid(2, cdiv(8 * 512, 64));
    gemm_fp_kernel<32><<<grid, 256, 0, stream>>>(g2, idx3, w3buf, f1, nullptr, nullptr, nullptr,
                                                 F1, fb1, g1, 512, 256, 256, 64, 0,
                                                 8 * 512, 128, 320);
  }

  // ---- FP0 ----
  knn3_lds_kernel<<<128, 256, 0, stream>>>(xyz, x1, 4096, 512, idx3, w3buf, 4096, 512);
  {
    dim3 grid(2, cdiv(8 * 4096, 64));
    gemm_fp_kernel<32><<<grid, 256, 0, stream>>>(g1, idx3, w3buf, nullptr, cls, xyz, nrm,
                                                 F0, fb0, g0, 4096, 512, 128, 22, 1,
                                                 8 * 4096, 128, 150);
  }

  // ---- seg head ----
  {
    dim3 grid(1, cdiv(8 * 4096, 64));
    gemm_plain_kernel<32><<<grid, 256, 0, stream>>>(g0, Wseg, bseg, out, 8 * 4096, 50, 128, 0);
  }
  // ---- out2 = transpose(g0) ----
  transpose_g0_kernel<<<dim3(128, 4, 8), 256, 0, stream>>>(g0, out + (size_t)8 * 4096 * 50);
}

// Round 11
// 1123.666 us; speedup vs baseline: 1.3526x; 1.3526x over previous
//
#include <hip/hip_runtime.h>
#include <float.h>

#define B8 8
#define NPTS 4096

// ---------------- split x[B,6,N] -> xyz[B,N,3], nrm[B,N,3] ----------------
__global__ void split_xyz_kernel(const float* __restrict__ x,
                                 float* __restrict__ xyz, float* __restrict__ nrm) {
  int g = blockIdx.x * 256 + threadIdx.x;
  if (g >= B8 * NPTS) return;
  int b = g / NPTS, n = g % NPTS;
  const float* xb = x + (size_t)b * 6 * NPTS;
  float* o1 = xyz + (size_t)g * 3;
  float* o2 = nrm + (size_t)g * 3;
  o1[0] = xb[0 * NPTS + n]; o1[1] = xb[1 * NPTS + n]; o1[2] = xb[2 * NPTS + n];
  o2[0] = xb[3 * NPTS + n]; o2[1] = xb[4 * NPTS + n]; o2[2] = xb[5 * NPTS + n];
}

// ---------------- DPP helpers ----------------
template <int CTRL, int RM>
__device__ __forceinline__ unsigned dppmov(unsigned v) {
  return (unsigned)__builtin_amdgcn_update_dpp((int)v, (int)v, CTRL, RM, 0xf, false);
}

template <int CTRL, int RM>
__device__ __forceinline__ void red_key_max(unsigned& kh, unsigned& kl) {
  unsigned oh = dppmov<CTRL, RM>(kh);
  unsigned ol = dppmov<CTRL, RM>(kl);
  unsigned long long ko = ((unsigned long long)oh << 32) | ol;
  unsigned long long k  = ((unsigned long long)kh << 32) | kl;
  bool c = ko > k;
  kh = c ? oh : kh;
  kl = c ? ol : kl;
}

template <int CTRL, int RM>
__device__ __forceinline__ void red_key_min(unsigned& kh, unsigned& kl) {
  unsigned oh = dppmov<CTRL, RM>(kh);
  unsigned ol = dppmov<CTRL, RM>(kl);
  unsigned long long ko = ((unsigned long long)oh << 32) | ol;
  unsigned long long k  = ((unsigned long long)kh << 32) | kl;
  bool c = ko < k;
  kh = c ? oh : kh;
  kl = c ? ol : kl;
}

#define WAVE_RED_MAX(kh, kl)            \
  red_key_max<0x111, 0xf>(kh, kl);      \
  red_key_max<0x112, 0xf>(kh, kl);      \
  red_key_max<0x114, 0xf>(kh, kl);      \
  red_key_max<0x118, 0xf>(kh, kl);      \
  red_key_max<0x142, 0xa>(kh, kl);      \
  red_key_max<0x143, 0xc>(kh, kl);

#define WAVE_RED_MIN(kh, kl)            \
  red_key_min<0x111, 0xf>(kh, kl);      \
  red_key_min<0x112, 0xf>(kh, kl);      \
  red_key_min<0x114, 0xf>(kh, kl);      \
  red_key_min<0x118, 0xf>(kh, kl);      \
  red_key_min<0x142, 0xa>(kh, kl);      \
  red_key_min<0x143, 0xc>(kh, kl);

// ---------------- FPS (SA1 only; deeper levels are prefixes of x1) ----------------
template <int BLOCK, int P>
__global__ __launch_bounds__(BLOCK) void fps4_kernel(const float* __restrict__ xyz,
                                                     int N, int S,
                                                     float* __restrict__ out_xyz) {
#pragma clang fp contract(off)
  constexpr int NW = BLOCK / 64;
  __shared__ float4 pts[BLOCK * P];
  __shared__ float4 sel[512];
  __shared__ alignas(16) unsigned long long wkey[2][NW];
  int b = blockIdx.x, t = threadIdx.x;
  const float* p = xyz + (size_t)b * N * 3;
  float px[P], py[P], pz[P], dist[P];
#pragma unroll
  for (int j = 0; j < P; ++j) {
    int idx = t + j * BLOCK;
    float a = p[3 * idx], bb = p[3 * idx + 1], c = p[3 * idx + 2];
    px[j] = a; py[j] = bb; pz[j] = c;
    pts[idx] = make_float4(a, bb, c, 0.f);
    dist[j] = 1e10f;
  }
  __syncthreads();
  float fx = p[0], fy = p[1], fz = p[2];
  for (int i = 0; i < S; ++i) {
    if (t == 0) sel[i] = make_float4(fx, fy, fz, 0.f);
    float bv = -1.0f;
    int bj = 0;
#pragma unroll
    for (int j = 0; j < P; ++j) {
      float dx = px[j] - fx, dy = py[j] - fy, dz = pz[j] - fz;
      float d = dx * dx + dy * dy + dz * dz;
      float nd = fminf(dist[j], d);
      dist[j] = nd;
      bool c = nd > bv;
      bv = c ? nd : bv;
      bj = c ? j : bj;
    }
    unsigned kh = __float_as_uint(bv);
    unsigned kl = (unsigned)(~(t + bj * BLOCK));
    WAVE_RED_MAX(kh, kl);
    int buf = i & 1;
    if ((t & 63) == 63)
      wkey[buf][t >> 6] = ((unsigned long long)kh << 32) | kl;
    __syncthreads();
    unsigned long long g = 0ull;
    const ulonglong2* wk2 = (const ulonglong2*)&wkey[buf][0];
#pragma unroll
    for (int w = 0; w < NW / 2; ++w) {
      ulonglong2 e = wk2[w];
      unsigned long long m = (e.x > e.y) ? e.x : e.y;
      g = (m > g) ? m : g;
    }
    int far = (int)~(unsigned)g;
    float4 f = pts[far];
    fx = f.x; fy = f.y; fz = f.z;
  }
  __syncthreads();
  for (int i = t; i < S; i += BLOCK) {
    float4 f = sel[i];
    float* o = out_xyz + ((size_t)b * S + i) * 3;
    o[0] = f.x; o[1] = f.y; o[2] = f.z;
  }
}

// ---------------- kNN k=20 for SA1 (M=4096, one wave/block) ----------------
__global__ __launch_bounds__(64) void knn20_kernel(const float* __restrict__ q,
                                                   const float* __restrict__ ref,
                                                   int S, int M, int* __restrict__ nidx,
                                                   int LDQ, int LDR) {
#pragma clang fp contract(off)
  int bs = blockIdx.x;
  int b = bs / S, s = bs % S;
  int t = threadIdx.x;
  __shared__ float sd[4096];
  const float* qp = q + ((size_t)b * LDQ + s) * 3;
  float qx = qp[0], qy = qp[1], qz = qp[2];
  float qq = qx * qx + qy * qy + qz * qz;
  const float* rp = ref + (size_t)b * LDR * 3;
  for (int i = t; i < M; i += 64) {
    float rx = rp[3 * i], ry = rp[3 * i + 1], rz = rp[3 * i + 2];
    float rr = rx * rx + ry * ry + rz * rz;
    float dot = qx * rx + qy * ry + qz * rz;
    sd[i] = qq - 2.0f * dot + rr;
  }
  __syncthreads();
  unsigned keep = 0;
  for (int k = 0; k < 20; ++k) {
    float bv = FLT_MAX;
    int bi = 0;
    for (int i = t; i < M; i += 64) {
      float v = sd[i];
      bool c = v < bv;
      bv = c ? v : bv;
      bi = c ? i : bi;
    }
    unsigned kh = __float_as_uint(bv), kl = (unsigned)bi;
    WAVE_RED_MIN(kh, kl);
    unsigned w = (unsigned)__builtin_amdgcn_readlane((int)kl, 63);
    if (t == k) keep = w;
    if (t == 0) sd[w] = FLT_MAX;
    __syncthreads();
  }
  if (t < 20) nidx[(size_t)bs * 20 + t] = (int)keep;
}

// ---------------- knn3 select+store helper ----------------
__device__ __forceinline__ void knn3_store(int g, const float* rx3,
                                           float qx, float qy, float qz,
                                           int i0, int i1, int i2,
                                           int* __restrict__ idx3,
                                           float* __restrict__ w3) {
#pragma clang fp contract(off)
  int ii[3] = {i0, i1, i2};
  float w[3];
  float wsum = 0.0f;
#pragma unroll
  for (int k = 0; k < 3; ++k) {
    const float* r = rx3 + (size_t)ii[k] * 3;
    float dx = r[0] - qx, dy = r[1] - qy, dz = r[2] - qz;
    float d = dx * dx + dy * dy + dz * dz;
    w[k] = 1.0f / (d + 1e-8f);
    wsum += w[k];
  }
#pragma unroll
  for (int k = 0; k < 3; ++k) {
    idx3[(size_t)g * 3 + k] = ii[k];
    w3[(size_t)g * 3 + k] = w[k] / wsum;
  }
}

// ---------------- fused neighbor kernel: SA2/3/4 knn20 + all knn3 ----------------
// Regions by blockIdx (all depend only on x1 coordinates + xyz for FP0):
//   [0,512)    SA2 knn20 (S=256,M=512), 4 waves/block, per-wave LDS slice
//   [512,768)  SA3 knn20 (S=128,M=256)
//   [768,896)  SA4 knn20 (S=64, M=128)
//   [896,900)  FP3 knn3 plain (Sq=128,M=64)
//   [900,908)  FP2 knn3 LDS  (Sq=256,M=128)
//   [908,924)  FP1 knn3 LDS  (Sq=512,M=256)
//   [924,1052) FP0 knn3 LDS  (Sq=4096,M=512, q=xyz)
// knn20 regions use __syncthreads() per pass: barrier = compiler+HW fence for
// the cross-lane swd[w] update (wave-sync-without-barrier was R10's bug).
__global__ __launch_bounds__(256) void neighbors_kernel(
    const float* __restrict__ xyz, const float* __restrict__ x1,
    int* __restrict__ nidx2, int* __restrict__ nidx3, int* __restrict__ nidx4,
    int* __restrict__ idx3_3, float* __restrict__ w3_3,
    int* __restrict__ idx3_2, float* __restrict__ w3_2,
    int* __restrict__ idx3_1, float* __restrict__ w3_1,
    int* __restrict__ idx3_0, float* __restrict__ w3_0) {
#pragma clang fp contract(off)
  __shared__ float4 smem4[512];          // 8 KB, aliased per region
  int blk = blockIdx.x, tid = threadIdx.x;

  if (blk < 896) {  // ---- knn20 regions ----
    int S, M, qid;
    int* nout;
    const int wv = tid >> 6, t64 = tid & 63;
    if (blk < 512)      { S = 256; M = 512; qid = blk * 4 + wv;         nout = nidx2; }
    else if (blk < 768) { S = 128; M = 256; qid = (blk - 512) * 4 + wv; nout = nidx3; }
    else                { S = 64;  M = 128; qid = (blk - 768) * 4 + wv; nout = nidx4; }
    float* swd = (float*)smem4 + wv * M;
    int b = qid / S, s = qid % S;
    const float* qp = x1 + ((size_t)b * 512 + s) * 3;
    float qx = qp[0], qy = qp[1], qz = qp[2];
    float qq = qx * qx + qy * qy + qz * qz;
    const float* rp = x1 + (size_t)b * 512 * 3;
    for (int i = t64; i < M; i += 64) {
      float rx = rp[3 * i], ry = rp[3 * i + 1], rz = rp[3 * i + 2];
      float rr = rx * rx + ry * ry + rz * rz;
      float dot = qx * rx + qy * ry + qz * rz;
      swd[i] = qq - 2.0f * dot + rr;
    }
    __syncthreads();
    unsigned keep = 0;
    for (int k = 0; k < 20; ++k) {
      float bv = FLT_MAX;
      int bi = 0;
      for (int i = t64; i < M; i += 64) {
        float v = swd[i];
        bool c = v < bv;
        bv = c ? v : bv;
        bi = c ? i : bi;
      }
      unsigned kh = __float_as_uint(bv), kl = (unsigned)bi;
      WAVE_RED_MIN(kh, kl);
      unsigned w = (unsigned)__builtin_amdgcn_readlane((int)kl, 63);
      if (t64 == k) keep = w;
      if (t64 == 0) swd[w] = FLT_MAX;
      __syncthreads();   // uniform across the block's 4 waves (same trip count)
    }
    if (t64 < 20) nout[(size_t)qid * 20 + t64] = (int)keep;
    return;
  }

  if (blk < 900) {  // ---- FP3 knn3, plain VMEM scan (M=64) ----
    int g = (blk - 896) * 256 + tid;     // < 1024
    int Sq = 128, M = 64;
    int b = g / Sq, s = g % Sq;
    const float* qp = x1 + ((size_t)b * 512 + s) * 3;
    float qx = qp[0], qy = qp[1], qz = qp[2];
    float qq = qx * qx + qy * qy + qz * qz;
    const float* rp = x1 + (size_t)b * 512 * 3;
    float v0 = FLT_MAX, v1 = FLT_MAX, v2 = FLT_MAX;
    int i0 = 0, i1 = 0, i2 = 0;
    for (int i = 0; i < M; ++i) {
      float rx = rp[3 * i], ry = rp[3 * i + 1], rz = rp[3 * i + 2];
      float d = qq - 2.0f * (qx * rx + qy * ry + qz * rz) + (rx * rx + ry * ry + rz * rz);
      if (d < v2) {
        if (d < v1) {
          if (d < v0) { v2 = v1; i2 = i1; v1 = v0; i1 = i0; v0 = d; i0 = i; }
          else { v2 = v1; i2 = i1; v1 = d; i1 = i; }
        } else { v2 = d; i2 = i; }
      }
    }
    knn3_store(g, rp, qx, qy, qz, i0, i1, i2, idx3_3, w3_3);
    return;
  }

  // ---- knn3 LDS regions (block-uniform batch) ----
  int g, Sq, M, LDQ;
  int* oidx;
  float* ow;
  const float* q;
  if (blk < 908)      { g = (blk - 900) * 256 + tid; Sq = 256;  M = 128; oidx = idx3_2; ow = w3_2; q = x1;  LDQ = 512; }
  else if (blk < 924) { g = (blk - 908) * 256 + tid; Sq = 512;  M = 256; oidx = idx3_1; ow = w3_1; q = x1;  LDQ = 512; }
  else                { g = (blk - 924) * 256 + tid; Sq = 4096; M = 512; oidx = idx3_0; ow = w3_0; q = xyz; LDQ = 4096; }
  int b = g / Sq, s = g % Sq;
  const float* rp = x1 + (size_t)b * 512 * 3;
  for (int i = tid; i < M; i += 256) {
    float rx = rp[3 * i], ry = rp[3 * i + 1], rz = rp[3 * i + 2];
    smem4[i] = make_float4(rx, ry, rz, rx * rx + ry * ry + rz * rz);
  }
  __syncthreads();
  const float* qp = q + ((size_t)b * LDQ + s) * 3;
  float qx = qp[0], qy = qp[1], qz = qp[2];
  float qq = qx * qx + qy * qy + qz * qz;
  float v0 = FLT_MAX, v1 = FLT_MAX, v2 = FLT_MAX;
  int i0 = 0, i1 = 0, i2 = 0;
  for (int i = 0; i < M; ++i) {
    float4 r = smem4[i];
    float d = qq - 2.0f * (qx * r.x + qy * r.y + qz * r.z) + r.w;
    if (d < v2) {
      if (d < v1) {
        if (d < v0) { v2 = v1; i2 = i1; v1 = v0; i1 = i0; v0 = d; i0 = i; }
        else { v2 = v1; i2 = i1; v1 = d; i1 = i; }
      } else { v2 = d; i2 = i; }
    }
  }
  {
    int ii[3] = {i0, i1, i2};
    float w[3];
    float wsum = 0.0f;
#pragma unroll
    for (int k = 0; k < 3; ++k) {
      float4 r = smem4[ii[k]];
      float dx = r.x - qx, dy = r.y - qy, dz = r.z - qz;
      float d = dx * dx + dy * dy + dz * dz;
      w[k] = 1.0f / (d + 1e-8f);
      wsum += w[k];
    }
#pragma unroll
    for (int k = 0; k < 3; ++k) {
      oidx[(size_t)g * 3 + k] = ii[k];
      ow[(size_t)g * 3 + k] = w[k] / wsum;
    }
  }
}

// ---------------- R8 double-buffered GEMM core (BK=16, one barrier/step) ----------------
#define GEMM_STAGE(k0v, ...)                                                      \
    _Pragma("unroll")                                                             \
    for (int u = 0; u < 4; ++u) {                                                 \
      int l = (int)threadIdx.x + u * 256;                                         \
      int m = l >> 4, kk = l & 15;                                                \
      int rr = rowBase + m, kq = (k0v) + kk;                                      \
      float v = 0.0f;                                                             \
      if (rr < Mrows && kq < K) { __VA_ARGS__ }                                   \
      areg[u] = v;                                                                \
    }                                                                             \
    _Pragma("unroll")                                                             \
    for (int u = 0; u < 4; ++u) {                                                 \
      int l = (int)threadIdx.x + u * 256;                                         \
      int kk = l >> 6, n = l & 63;                                                \
      int kq = (k0v) + kk, cc = colBase + n;                                      \
      breg[u] = (kq < K && cc < N) ? Wm[(size_t)kq * N + cc] : 0.0f;              \
    }

#define GEMM_WRITE_LDS(bufv)                                                      \
    _Pragma("unroll")                                                             \
    for (int u = 0; u < 4; ++u) {                                                 \
      int l = (int)threadIdx.x + u * 256;                                         \
      As[bufv][l & 15][l >> 4] = areg[u];                                         \
    }                                                                             \
    _Pragma("unroll")                                                             \
    for (int u = 0; u < 4; ++u) {                                                 \
      int l = (int)threadIdx.x + u * 256;                                         \
      Bs[bufv][l >> 6][l & 63] = breg[u];                                         \
    }

#define GEMM_MAIN(...)                                                            \
  __shared__ alignas(16) float As[2][16][68];                                     \
  __shared__ float Bs[2][16][64];                                                 \
  int tx = threadIdx.x & 15, ty = threadIdx.x >> 4;                               \
  int rowBase = blockIdx.y * 64;                                                  \
  int colBase = blockIdx.x * 64;                                                  \
  float acc[4][4] = {};                                                           \
  float areg[4], breg[4];                                                         \
  GEMM_STAGE(0, __VA_ARGS__)                                                      \
  GEMM_WRITE_LDS(0)                                                               \
  __syncthreads();                                                                \
  int cur = 0;                                                                    \
  for (int k0 = 0; k0 < K; k0 += 16) {                                            \
    int nxt = cur ^ 1;                                                            \
    bool more = (k0 + 16 < K);                                                    \
    if (more) { GEMM_STAGE(k0 + 16, __VA_ARGS__) }                                \
    _Pragma("unroll")                                                             \
    for (int kk = 0; kk < 16; ++kk) {                                             \
      const float4 av = *reinterpret_cast<const float4*>(&As[cur][kk][ty * 4]);   \
      const float4 bv = *reinterpret_cast<const float4*>(&Bs[cur][kk][tx * 4]);   \
      acc[0][0] += av.x * bv.x; acc[0][1] += av.x * bv.y;                         \
      acc[0][2] += av.x * bv.z; acc[0][3] += av.x * bv.w;                         \
      acc[1][0] += av.y * bv.x; acc[1][1] += av.y * bv.y;                         \
      acc[1][2] += av.y * bv.z; acc[1][3] += av.y * bv.w;                         \
      acc[2][0] += av.z * bv.x; acc[2][1] += av.z * bv.y;                         \
      acc[2][2] += av.z * bv.z; acc[2][3] += av.z * bv.w;                         \
      acc[3][0] += av.w * bv.x; acc[3][1] += av.w * bv.y;                         \
      acc[3][2] += av.w * bv.z; acc[3][3] += av.w * bv.w;                         \
    }                                                                             \
    if (more) { GEMM_WRITE_LDS(nxt) }                                             \
    __syncthreads();                                                              \
    cur = nxt;                                                                    \
  }

#define GEMM_EPI_STORE                                                            \
  _Pragma("unroll")                                                               \
  for (int i = 0; i < 4; ++i) {                                                   \
    int row = rowBase + ty * 4 + i;                                               \
    if (row >= Mrows) continue;                                                   \
    _Pragma("unroll")                                                             \
    for (int j = 0; j < 4; ++j) {                                                 \
      int col = colBase + tx * 4 + j;                                             \
      if (col >= N) continue;                                                     \
      float v = acc[i][j] + bias[col];                                            \
      if (RELU) v = fmaxf(v, 0.0f);                                               \
      C[(size_t)row * N + col] = v;                                               \
    }                                                                             \
  }

// plain GEMM (seg head)
__global__ __launch_bounds__(256) void gemm_kernel(const float* __restrict__ A,
                                                   const float* __restrict__ Wm,
                                                   const float* __restrict__ bias,
                                                   float* __restrict__ C,
                                                   int Mrows, int N, int K, int RELU) {
  GEMM_MAIN( v = A[(size_t)rr * K + kq]; )
  GEMM_EPI_STORE
}

// SA GEMM: fused grouping gather + ReLU + maxpool-over-20 via atomic-max.
// fOut must be zero-initialized; relu >= 0 so float-bit int max == float max.
__global__ __launch_bounds__(256) void gemm_sa_kernel(
    const float* __restrict__ xyz, const float* __restrict__ feats,
    const float* __restrict__ new_xyz, const int* __restrict__ nidx,
    const float* __restrict__ Wm, const float* __restrict__ bias,
    float* __restrict__ fOut, int Mref, int LDR, int S, int LDQ, int Cf,
    int Mrows, int N, int K) {
  GEMM_MAIN(
    int bs = rr / 20;
    int s_ = bs % S;
    int b = bs / S;
    int id = nidx[rr];
    if (kq < 3)
      v = xyz[((size_t)b * LDR + id) * 3 + kq] - new_xyz[((size_t)b * LDQ + s_) * 3 + kq];
    else
      v = feats[((size_t)b * Mref + id) * Cf + (kq - 3)];
  )
  // epilogue: per-block partial max per (group, col) in LDS, then global atomics
  __shared__ int smax[4][64];           // 64 rows span exactly 4 groups of 20
  int gBase = rowBase / 20;
  int nG = (rowBase + 63) / 20 - gBase + 1;
  for (int l = threadIdx.x; l < nG * 64; l += 256) smax[l >> 6][l & 63] = 0;
  __syncthreads();
#pragma unroll
  for (int i = 0; i < 4; ++i) {
    int row = rowBase + ty * 4 + i;
    if (row >= Mrows) continue;
    int gl = row / 20 - gBase;
#pragma unroll
    for (int j = 0; j < 4; ++j) {
      int col = colBase + tx * 4 + j;
      if (col >= N) continue;
      float v = fmaxf(acc[i][j] + bias[col], 0.0f);
      atomicMax(&smax[gl][col - colBase], __float_as_int(v));
    }
  }
  __syncthreads();
  for (int l = threadIdx.x; l < nG * 64; l += 256) {
    int g = gBase + (l >> 6), c = colBase + (l & 63);
    if (c < N) atomicMax((int*)&fOut[(size_t)g * N + c], smax[l >> 6][l & 63]);
  }
}

// FP GEMM with fused 3-NN interp + skip concat
__global__ __launch_bounds__(256) void gemm_fp_kernel(
    const float* __restrict__ fr, const int* __restrict__ idx3,
    const float* __restrict__ w3, const float* __restrict__ skip,
    const float* __restrict__ cls, const float* __restrict__ xyzq,
    const float* __restrict__ nrmq,
    const float* __restrict__ Wm, const float* __restrict__ bias,
    float* __restrict__ C, int Sq, int Mr, int Cr, int Cs, int mode,
    int Mrows, int N, int K) {
  const int RELU = 1;
  GEMM_MAIN(
    int bs = rr;
    int b = bs / Sq;
    if (kq < Cr) {
      const int* ii = idx3 + (size_t)bs * 3;
      const float* ww = w3 + (size_t)bs * 3;
      const float* fb = fr + (size_t)b * Mr * Cr;
      v = ww[0] * fb[(size_t)ii[0] * Cr + kq];
      v += ww[1] * fb[(size_t)ii[1] * Cr + kq];
      v += ww[2] * fb[(size_t)ii[2] * Cr + kq];
    } else {
      int cc = kq - Cr;
      if (mode == 0) {
        v = skip[(size_t)bs * Cs + cc];
      } else {
        if (cc < 16) v = cls[(size_t)b * 16 + cc];
        else if (cc < 19) v = xyzq[(size_t)bs * 3 + (cc - 16)];
        else v = nrmq[(size_t)bs * 3 + (cc - 19)];
      }
    }
  )
  GEMM_EPI_STORE
}

// ---------------- transpose g0 [B,N,128] -> out2 [B,128,N] ----------------
__global__ __launch_bounds__(256) void transpose_g0_kernel(const float* __restrict__ g0,
                                                           float* __restrict__ out2) {
  __shared__ float tile[32][33];
  int n0 = blockIdx.x * 32, c0 = blockIdx.y * 32, b = blockIdx.z;
  int tx = threadIdx.x & 31, ty = threadIdx.x >> 5;
#pragma unroll
  for (int j = 0; j < 32; j += 8)
    tile[ty + j][tx] = g0[((size_t)b * NPTS + n0 + ty + j) * 128 + c0 + tx];
  __syncthreads();
#pragma unroll
  for (int j = 0; j < 32; j += 8)
    out2[((size_t)b * 128 + c0 + ty + j) * NPTS + n0 + tx] = tile[tx][ty + j];
}

// ---------------- host-side orchestration ----------------
static inline int cdiv(int a, int b) { return (a + b - 1) / b; }

extern "C" void kernel_launch(void* const* d_in, const int* in_sizes, int n_in,
                              void* d_out, int out_size, void* d_ws, size_t ws_size,
                              hipStream_t stream) {
  const float* x    = (const float*)d_in[0];
  const float* cls  = (const float*)d_in[1];
  const float* W0 = (const float*)d_in[2];  const float* b0 = (const float*)d_in[3];
  const float* W1 = (const float*)d_in[4];  const float* b1 = (const float*)d_in[5];
  const float* W2 = (const float*)d_in[6];  const float* b2 = (const float*)d_in[7];
  const float* W3 = (const float*)d_in[8];  const float* b3 = (const float*)d_in[9];
  const float* F3 = (const float*)d_in[10]; const float* fb3 = (const float*)d_in[11];
  const float* F2 = (const float*)d_in[12]; const float* fb2 = (const float*)d_in[13];
  const float* F1 = (const float*)d_in[14]; const float* fb1 = (const float*)d_in[15];
  const float* F0 = (const float*)d_in[16]; const float* fb0 = (const float*)d_in[17];
  const float* Wseg = (const float*)d_in[18]; const float* bseg = (const float*)d_in[19];
  float* out = (float*)d_out;

  float* ws = (float*)d_ws;
  size_t off = 0;
  auto alloc = [&](size_t n) { float* p = ws + off; off += (n + 3) & ~(size_t)3; return p; };
  float* xyz = alloc(8 * 4096 * 3);
  float* nrm = alloc(8 * 4096 * 3);
  float* x1 = alloc(8 * 512 * 3);          // x2/x3/x4 are per-batch PREFIXES of x1
  float* f1 = alloc(8 * 512 * 64);         // f1..f4 contiguous: one memset
  float* f2 = alloc(8 * 256 * 128);
  float* f3 = alloc(8 * 128 * 256);
  float* f4 = alloc(8 * 64 * 512);
  float* g3 = alloc(8 * 128 * 512);
  float* g2 = alloc(8 * 256 * 256);
  float* g1 = alloc(8 * 512 * 128);
  float* g0 = alloc(8 * 4096 * 128);
  int* nidx1 = (int*)alloc(8 * 512 * 20);
  int* nidx2 = (int*)alloc(8 * 256 * 20);
  int* nidx3 = (int*)alloc(8 * 128 * 20);
  int* nidx4 = (int*)alloc(8 * 64 * 20);
  int* idx3_3 = (int*)alloc(8 * 128 * 3);  float* w3_3 = alloc(8 * 128 * 3);
  int* idx3_2 = (int*)alloc(8 * 256 * 3);  float* w3_2 = alloc(8 * 256 * 3);
  int* idx3_1 = (int*)alloc(8 * 512 * 3);  float* w3_1 = alloc(8 * 512 * 3);
  int* idx3_0 = (int*)alloc(8 * 4096 * 3); float* w3_0 = alloc(8 * 4096 * 3);

  // zero f1..f4 (atomic-max targets; relu outputs >= 0 so 0-init is exact)
  hipMemsetAsync(f1, 0, (size_t)8 * (512 * 64 + 256 * 128 + 128 * 256 + 64 * 512) * 4, stream);

  split_xyz_kernel<<<cdiv(8 * 4096, 256), 256, 0, stream>>>(x, xyz, nrm);
  fps4_kernel<256, 16><<<8, 256, 0, stream>>>(xyz, 4096, 512, x1);
  knn20_kernel<<<8 * 512, 64, 0, stream>>>(x1, xyz, 512, 4096, nidx1, 512, 4096);
  neighbors_kernel<<<1052, 256, 0, stream>>>(xyz, x1, nidx2, nidx3, nidx4,
                                             idx3_3, w3_3, idx3_2, w3_2,
                                             idx3_1, w3_1, idx3_0, w3_0);

  // ---- SA1: Cin 6 -> 64, fused gather+GEMM+relu+maxpool ----
  {
    dim3 grid(1, cdiv(8 * 512 * 20, 64));
    gemm_sa_kernel<<<grid, 256, 0, stream>>>(xyz, nrm, x1, nidx1, W0, b0, f1,
                                             4096, 4096, 512, 512, 3,
                                             8 * 512 * 20, 64, 6);
  }
  // ---- SA2: Cin 67 -> 128 ----
  {
    dim3 grid(2, cdiv(8 * 256 * 20, 64));
    gemm_sa_kernel<<<grid, 256, 0, stream>>>(x1, f1, x1, nidx2, W1, b1, f2,
                                             512, 512, 256, 512, 64,
                                             8 * 256 * 20, 128, 67);
  }
  // ---- SA3: Cin 131 -> 256 ----
  {
    dim3 grid(4, cdiv(8 * 128 * 20, 64));
    gemm_sa_kernel<<<grid, 256, 0, stream>>>(x1, f2, x1, nidx3, W2, b2, f3,
                                             256, 512, 128, 512, 128,
                                             8 * 128 * 20, 256, 131);
  }
  // ---- SA4: Cin 259 -> 512 ----
  {
    dim3 grid(8, cdiv(8 * 64 * 20, 64));
    gemm_sa_kernel<<<grid, 256, 0, stream>>>(x1, f3, x1, nidx4, W3, b3, f4,
                                             128, 512, 64, 512, 256,
                                             8 * 64 * 20, 512, 259);
  }

  // ---- FP3 ----
  {
    dim3 grid(8, cdiv(8 * 128, 64));
    gemm_fp_kernel<<<grid, 256, 0, stream>>>(f4, idx3_3, w3_3, f3, nullptr, nullptr, nullptr,
                                             F3, fb3, g3, 128, 64, 512, 256, 0,
                                             8 * 128, 512, 768);
  }
  // ---- FP2 ----
  {
    dim3 grid(4, cdiv(8 * 256, 64));
    gemm_fp_kernel<<<grid, 256, 0, stream>>>(g3, idx3_2, w3_2, f2, nullptr, nullptr, nullptr,
                                             F2, fb2, g2, 256, 128, 512, 128, 0,
                                             8 * 256, 256, 640);
  }
  // ---- FP1 ----
  {
    dim3 grid(2, cdiv(8 * 512, 64));
    gemm_fp_kernel<<<grid, 256, 0, stream>>>(g2, idx3_1, w3_1, f1, nullptr, nullptr, nullptr,
                                             F1, fb1, g1, 512, 256, 256, 64, 0,
                                             8 * 512, 128, 320);
  }
  // ---- FP0 ----
  {
    dim3 grid(2, cdiv(8 * 4096, 64));
    gemm_fp_kernel<<<grid, 256, 0, stream>>>(g1, idx3_0, w3_0, nullptr, cls, xyz, nrm,
                                             F0, fb0, g0, 4096, 512, 128, 22, 1,
                                             8 * 4096, 128, 150);
  }

  // ---- seg head ----
  {
    dim3 grid(1, cdiv(8 * 4096, 64));
    gemm_kernel<<<grid, 256, 0, stream>>>(g0, Wseg, bseg, out, 8 * 4096, 50, 128, 0);
  }
  // ---- out2 = transpose(g0) ----
  transpose_g0_kernel<<<dim3(128, 4, 8), 256, 0, stream>>>(g0, out + (size_t)8 * 4096 * 50);
}